// Round 8
// baseline (218.769 us; speedup 1.0000x reference)
//
#include <hip/hip_runtime.h>
#include <math.h>

#define N_VOX 32768
#define N_EMB 8192
#define DIM 64
#define NCHUNK 4
#define CODES_PER_CHUNK (N_EMB / NCHUNK)       // 2048
#define TILES_PER_CHUNK (CODES_PER_CHUNK / 32) // 64
#define NTILES (N_EMB / 32)                    // 256
#define TILE_BYTES 12416                       // bh2[4K] | bh[4K] | bl[4K] | c0[128]
#define CHUNK_BYTES (TILES_PER_CHUNK * TILE_BYTES)

typedef _Float16 half8 __attribute__((ext_vector_type(8)));
typedef float floatx16 __attribute__((ext_vector_type(16)));

#define FP16_MIN_NORMAL 6.1035156e-5f
#define LO_SCALE 2048.0f

// -------- kernel A: fused esq + B-fragment stream build ----------------------
// 32x32x16 f16 B-frag per K-chunk o: lane l holds code n=l&31, k=o*16+(l>>5)*8+j.
// Tile (32 codes): [bh2 = 2048*bh | bh | bl = 2048*res | c0 = -1024*esq].
// 2048 scale is exact (power of 2); hi forced to 0 if subnormal so lo is exact.
__global__ __launch_bounds__(256) void cbprep_kernel(const float* __restrict__ cb,
                                                     char* __restrict__ stream,
                                                     float* __restrict__ esq) {
    int t    = blockIdx.x * 256 + threadIdx.x;   // 256 tiles * 64 lanes
    int l    = t & 63;
    int m    = l & 31;
    int kg   = l >> 5;
    int tile = t >> 6;                           // global tile 0..255
    char* tbase = stream + (size_t)tile * TILE_BYTES;
    int code = tile * 32 + m;

    float ss = 0.f;
    #pragma unroll
    for (int o = 0; o < 4; ++o) {
        const float* p = cb + (size_t)code * DIM + o * 16 + kg * 8;
        half8 h, h2, lo;
        #pragma unroll
        for (int j = 0; j < 8; ++j) {
            float x = p[j];
            ss = fmaf(x, x, ss);
            _Float16 hi = (_Float16)x;
            float hf = (float)hi;
            if (fabsf(hf) < FP16_MIN_NORMAL) { hi = (_Float16)0.f; hf = 0.f; }
            h[j]  = hi;
            h2[j] = (_Float16)(hf * LO_SCALE);          // exact
            lo[j] = (_Float16)((x - hf) * LO_SCALE);
        }
        *(half8*)(tbase +        o * 1024 + l * 16) = h2;
        *(half8*)(tbase + 4096 + o * 1024 + l * 16) = h;
        *(half8*)(tbase + 8192 + o * 1024 + l * 16) = lo;
    }
    ss += __shfl_xor(ss, 32, 64);                // both half-rows summed
    if (kg == 0) {
        esq[code] = ss;
        *(float*)(tbase + 12288 + m * 4) = -1024.0f * ss;
    }
}

// -------- kernel B: MFMA argmin scan, register-lean (<=128 regs forced) ------
// Block = 4 waves, same chunk (shared tile stream -> L1 reuse). Wave owns
// 32 rows x one chunk (2048 codes, 64 tiles). K-chunk-major B loads keep only
// 3 frags (12 VGPR) live. acc = 2048*(dot - esq/2) via B-side scale:
//   zh.bh2 + zl.bh + zh.bl  (zl, bl pre-scaled by 2048; bh2 = 2048*bh).
// Maximize acc, tie -> earlier tile / lower id. Same math class as R3-R7.
__global__ __launch_bounds__(256, 4) void scan_kernel(const float* __restrict__ z,
                                                      const char* __restrict__ stream,
                                                      int* __restrict__ cand_idx) {
    int tid   = threadIdx.x;
    int l     = tid & 63;
    int w     = tid >> 6;                        // wave 0..3
    int chunk = blockIdx.x & (NCHUNK - 1);
    int rg    = blockIdx.x >> 2;                 // 0..255, 128 rows per block
    int m     = l & 31;                          // A row in tile / B col (code)
    int kg    = l >> 5;
    int rowBase = rg * 128 + w * 32;             // wave's 32 rows

    // A fragments: zh (unscaled), zl = 2048*res (exact split)
    half8 zh[4], zl[4];
    const float* zrow = z + (size_t)(rowBase + m) * DIM + kg * 8;
    #pragma unroll
    for (int o = 0; o < 4; ++o) {
        const float* p = zrow + o * 16;
        #pragma unroll
        for (int j = 0; j < 8; ++j) {
            float x = p[j];
            _Float16 hi = (_Float16)x;
            float hf = (float)hi;
            if (fabsf(hf) < FP16_MIN_NORMAL) { hi = (_Float16)0.f; hf = 0.f; }
            zh[o][j] = hi;
            zl[o][j] = (_Float16)((x - hf) * LO_SCALE);
        }
    }

    const char* tb = stream + (size_t)chunk * CHUNK_BYTES;

    float best[16];
    int   bt[16];
    #pragma unroll
    for (int i = 0; i < 16; ++i) { best[i] = -3.4e38f; bt[i] = 0; }

    for (int t = 0; t < TILES_PER_CHUNK; ++t) {
        float c0 = *(const float*)(tb + 12288 + m * 4);   // -1024*esq[code]
        floatx16 acc;
        #pragma unroll
        for (int i = 0; i < 16; ++i) acc[i] = c0;
        #pragma unroll
        for (int o = 0; o < 4; ++o) {
            half8 bh2 = *(const half8*)(tb +        o * 1024 + l * 16);
            half8 bh  = *(const half8*)(tb + 4096 + o * 1024 + l * 16);
            half8 bl  = *(const half8*)(tb + 8192 + o * 1024 + l * 16);
            acc = __builtin_amdgcn_mfma_f32_32x32x16_f16(zh[o], bh2, acc, 0, 0, 0);
            acc = __builtin_amdgcn_mfma_f32_32x32x16_f16(zl[o], bh,  acc, 0, 0, 0);
            acc = __builtin_amdgcn_mfma_f32_32x32x16_f16(zh[o], bl,  acc, 0, 0, 0);
        }
        #pragma unroll
        for (int i = 0; i < 16; ++i)
            if (acc[i] > best[i]) { best[i] = acc[i]; bt[i] = t; }
        tb += TILE_BYTES;
    }

    // Cross-lane argmax over the 32 cols (lane bits 0..4); tie -> lower index.
    // Lanes 0-31 (kg=0) and 32-63 (kg=1) hold different rows; xor<32 keeps them
    // separate, both halves write their own rows (validated R5 mapping).
    #pragma unroll
    for (int i = 0; i < 16; ++i) {
        float v  = best[i];
        int   id = bt[i] * 32 + m;               // code index within chunk
        #pragma unroll
        for (int off = 1; off < 32; off <<= 1) {
            float ov = __shfl_xor(v, off, 64);
            int   oi = __shfl_xor(id, off, 64);
            if (ov > v || (ov == v && oi < id)) { v = ov; id = oi; }
        }
        if (m == 0) {
            int row = rowBase + (i & 3) + 8 * (i >> 2) + 4 * kg;
            cand_idx[chunk * N_VOX + row] = chunk * CODES_PER_CHUNK + id;
        }
    }
}

// -------- kernel C: exact fp32 re-score, wave per row ------------------------
// 64 lanes = 4 candidates x 16 dim-segments (4 floats each). Shuffle-tree dot;
// cross-candidate min with id tie-break (ids ascend with chunk -> first occ.).
__global__ __launch_bounds__(256) void finalize_kernel(const float* __restrict__ z,
                                                       const float* __restrict__ cb,
                                                       const float* __restrict__ esq,
                                                       const int* __restrict__ cand_idx,
                                                       float* __restrict__ out,
                                                       float* __restrict__ partials) {
    int tid  = threadIdx.x;
    int l    = tid & 63;
    int w    = tid >> 6;
    int row  = blockIdx.x * 4 + w;
    int c    = l >> 4;                 // candidate 0..3
    int s    = l & 15;                 // dim segment (4 floats)

    int id = cand_idx[c * N_VOX + row];

    const float4 zv = ((const float4*)(z  + (size_t)row * DIM))[s];
    const float4 ev = ((const float4*)(cb + (size_t)id  * DIM))[s];
    float p = zv.x*ev.x + zv.y*ev.y + zv.z*ev.z + zv.w*ev.w;
    #pragma unroll
    for (int off = 1; off < 16; off <<= 1)
        p += __shfl_xor(p, off, 16);   // full dot in all 16 lanes of the group

    float score = esq[id] - 2.0f * p;
    #pragma unroll
    for (int off = 16; off < 64; off <<= 1) {
        float ov = __shfl_xor(score, off, 64);
        int   oi = __shfl_xor(id, off, 64);
        if (ov < score || (ov == score && oi < id)) { score = ov; id = oi; }
    }
    // all 64 lanes hold the winning id for this row

    if (l == 0)
        out[(size_t)N_VOX * DIM + 2 + row] = (float)id;

    // cooperative gather+write: lane handles element l
    float zs = z[(size_t)row * DIM + l];
    float qv = cb[(size_t)id * DIM + l];
    float d  = qv - zs;
    out[(size_t)row * DIM + l] = zs + d;   // mirrors reference z + (q - z)
    float ss = d * d;
    #pragma unroll
    for (int off = 1; off < 64; off <<= 1)
        ss += __shfl_xor(ss, off, 64);

    __shared__ float red[4];
    if (l == 0) red[w] = ss;
    __syncthreads();
    if (tid == 0)
        partials[blockIdx.x] = (red[0] + red[1]) + (red[2] + red[3]);
}

// -------- kernel D: reduce 8192 partials -> both losses --------
__global__ __launch_bounds__(256) void loss_kernel(const float* __restrict__ partials,
                                                   float* __restrict__ out) {
    float s = 0.f;
    #pragma unroll
    for (int i = 0; i < 32; ++i)
        s += partials[threadIdx.x + i * 256];
    __shared__ float red[256];
    red[threadIdx.x] = s;
    __syncthreads();
    #pragma unroll
    for (int st = 128; st > 0; st >>= 1) {
        if (threadIdx.x < st) red[threadIdx.x] += red[threadIdx.x + st];
        __syncthreads();
    }
    if (threadIdx.x == 0) {
        float mean = red[0] / (float)((size_t)N_VOX * DIM);
        out[(size_t)N_VOX * DIM + 0] = mean;
        out[(size_t)N_VOX * DIM + 1] = mean;
    }
}

extern "C" void kernel_launch(void* const* d_in, const int* in_sizes, int n_in,
                              void* d_out, int out_size, void* d_ws, size_t ws_size,
                              hipStream_t stream) {
    const float* z  = (const float*)d_in[0];   // [32768, 64]
    const float* cb = (const float*)d_in[1];   // [8192, 64]
    float* out = (float*)d_out;

    // ws: stream [256*12416 = 3,178,496 B] | esq [32 KB] | cand_idx [512 KB] | partials [32 KB]
    char*  bstream  = (char*)d_ws;
    float* esq      = (float*)(bstream + (size_t)NTILES * TILE_BYTES);
    int*   cand_idx = (int*)(esq + N_EMB);
    float* partials = (float*)(cand_idx + (size_t)NCHUNK * N_VOX);

    cbprep_kernel  <<<dim3(NTILES * 64 / 256), dim3(256), 0, stream>>>(cb, bstream, esq);
    scan_kernel    <<<dim3((N_VOX / 128) * NCHUNK), dim3(256), 0, stream>>>(z, bstream, cand_idx);
    finalize_kernel<<<dim3(N_VOX / 4), dim3(256), 0, stream>>>(z, cb, esq, cand_idx, out, partials);
    loss_kernel    <<<1, 256, 0, stream>>>(partials, out);
}

// Round 9
// 190.995 us; speedup vs baseline: 1.1454x; 1.1454x over previous
//
#include <hip/hip_runtime.h>
#include <math.h>

#define N_VOX 32768
#define N_EMB 8192
#define DIM 64
#define NCHUNK 8
#define CODES_PER_CHUNK (N_EMB / NCHUNK)       // 1024
#define TILES_PER_CHUNK (CODES_PER_CHUNK / 32) // 32
#define NTILES (N_EMB / 32)                    // 256
#define TILE_BYTES 8192                        // bh[4x1KB] | bl[4x1KB]
#define CHUNK_BYTES (TILES_PER_CHUNK * TILE_BYTES)

typedef _Float16 half8 __attribute__((ext_vector_type(8)));
typedef float floatx16 __attribute__((ext_vector_type(16)));

#define FP16_MIN_NORMAL 6.1035156e-5f
#define LO_SCALE 2048.0f

// -------- kernel A: fused esq + B-fragment stream build ----------------------
// 32x32x16 f16 B-frag per K-chunk o: lane l holds code n=l&31, k=o*16+(l>>5)*8+j.
// Tile (32 codes): [bh o=0..3 | bl o=0..3], each frag 1KB (lane l's half8 at l*16).
// c0arr[code] = -1024*esq (separate compact array, read by scan from global).
__global__ __launch_bounds__(256) void cbprep_kernel(const float* __restrict__ cb,
                                                     char* __restrict__ stream,
                                                     float* __restrict__ esq,
                                                     float* __restrict__ c0arr) {
    int t    = blockIdx.x * 256 + threadIdx.x;   // 256 tiles * 64 lanes
    int l    = t & 63;
    int m    = l & 31;
    int kg   = l >> 5;
    int tile = t >> 6;                           // global tile 0..255
    char* tbase = stream + (size_t)tile * TILE_BYTES;
    int code = tile * 32 + m;

    float ss = 0.f;
    #pragma unroll
    for (int o = 0; o < 4; ++o) {
        const float* p = cb + (size_t)code * DIM + o * 16 + kg * 8;
        half8 h, lo;
        #pragma unroll
        for (int j = 0; j < 8; ++j) {
            float x = p[j];
            ss = fmaf(x, x, ss);
            _Float16 hi = (_Float16)x;
            float hf = (float)hi;
            if (fabsf(hf) < FP16_MIN_NORMAL) { hi = (_Float16)0.f; hf = 0.f; }
            h[j]  = hi;
            lo[j] = (_Float16)((x - hf) * LO_SCALE);
        }
        *(half8*)(tbase +        o * 1024 + l * 16) = h;
        *(half8*)(tbase + 4096 + o * 1024 + l * 16) = lo;
    }
    ss += __shfl_xor(ss, 32, 64);                // both half-rows summed
    if (kg == 0) {
        esq[code]   = ss;
        c0arr[code] = -1024.0f * ss;
    }
}

// -------- kernel B: MFMA argmin scan, LDS-staged double-buffered B -----------
// Block = 4 waves, same chunk. Wave owns 32 rows x one chunk (1024 codes,
// 32 tiles). Per tile: 8KB staged global->LDS (global_load_lds x2/wave),
// consumed by all 4 waves via ds_read_b128. acc = 2048*(dot - esq/2) with
// A-side scale (zhs=2048*zh exact). Maximize, tie -> earlier tile/lower id.
// Math identical to validated R5/R7; reduce mapping = validated R8 (rt=1).
__global__ __launch_bounds__(256, 3) void scan_kernel(const float* __restrict__ z,
                                                      const char* __restrict__ stream,
                                                      const float* __restrict__ c0arr,
                                                      int* __restrict__ cand_idx) {
    __shared__ __align__(16) char lds[2 * TILE_BYTES];
    int tid   = threadIdx.x;
    int l     = tid & 63;
    int w     = tid >> 6;                        // wave 0..3
    int chunk = blockIdx.x & (NCHUNK - 1);
    int rg    = blockIdx.x >> 3;                 // 0..255, 128 rows per block
    int m     = l & 31;                          // A row in tile / B col (code)
    int kg    = l >> 5;
    int rowBase = rg * 128 + w * 32;             // wave's 32 rows

    // A fragments: zh (unscaled), zl = 2048*res, zhs = 2048*zh (exact shift)
    half8 zh[4], zl[4], zhs[4];
    const float* zrow = z + (size_t)(rowBase + m) * DIM + kg * 8;
    #pragma unroll
    for (int o = 0; o < 4; ++o) {
        const float* p = zrow + o * 16;
        #pragma unroll
        for (int j = 0; j < 8; ++j) {
            float x = p[j];
            _Float16 hi = (_Float16)x;
            float hf = (float)hi;
            if (fabsf(hf) < FP16_MIN_NORMAL) { hi = (_Float16)0.f; hf = 0.f; }
            zh[o][j] = hi;
            zl[o][j] = (_Float16)((x - hf) * LO_SCALE);
        }
        zhs[o] = zh[o] * (_Float16)2048.0f;
    }

    const char*  sbase = stream + (size_t)chunk * CHUNK_BYTES;
    const float* c0p   = c0arr + chunk * CODES_PER_CHUNK;

    float best[16];
    int   bt[16];
    #pragma unroll
    for (int i = 0; i < 16; ++i) { best[i] = -3.4e38f; bt[i] = 0; }

    // stage one 8KB tile: wave w issues segs {w, w+4} (1KB each, lane l -> +l*16)
#define STAGE(gt, lb)                                                              \
    do {                                                                           \
        _Pragma("unroll")                                                          \
        for (int _s = w; _s < 8; _s += 4) {                                        \
            const char* _g = (gt) + _s * 1024 + l * 16;                            \
            char*       _d = (lb) + _s * 1024 + l * 16;                            \
            __builtin_amdgcn_global_load_lds(                                      \
                (const __attribute__((address_space(1))) void*)_g,                 \
                (__attribute__((address_space(3))) void*)_d, 16, 0, 0);            \
        }                                                                          \
    } while (0)

    STAGE(sbase, lds);                           // tile 0 -> buf 0
    float c0 = c0p[m];                           // tile 0's -1024*esq
    __syncthreads();                             // staging complete

    for (int t = 0; t < TILES_PER_CHUNK; ++t) {
        if (t + 1 < TILES_PER_CHUNK)
            STAGE(sbase + (size_t)(t + 1) * TILE_BYTES, lds + ((t + 1) & 1) * TILE_BYTES);
        float c0n = (t + 1 < TILES_PER_CHUNK) ? c0p[(t + 1) * 32 + m] : 0.f;

        const char* lb = lds + (t & 1) * TILE_BYTES;
        half8 bh[4], bl[4];
        #pragma unroll
        for (int o = 0; o < 4; ++o) {
            bh[o] = *(const half8*)(lb +        o * 1024 + l * 16);
            bl[o] = *(const half8*)(lb + 4096 + o * 1024 + l * 16);
        }

        floatx16 acc;
        #pragma unroll
        for (int i = 0; i < 16; ++i) acc[i] = c0;
        #pragma unroll
        for (int o = 0; o < 4; ++o) {
            acc = __builtin_amdgcn_mfma_f32_32x32x16_f16(zhs[o], bh[o], acc, 0, 0, 0);
            acc = __builtin_amdgcn_mfma_f32_32x32x16_f16(zl[o],  bh[o], acc, 0, 0, 0);
            acc = __builtin_amdgcn_mfma_f32_32x32x16_f16(zh[o],  bl[o], acc, 0, 0, 0);
        }
        #pragma unroll
        for (int i = 0; i < 16; ++i)
            if (acc[i] > best[i]) { best[i] = acc[i]; bt[i] = t; }

        c0 = c0n;
        __syncthreads();   // t+1 staging landed; all waves done reading buf t&1
    }
#undef STAGE

    // Cross-lane argmax over the 32 cols (lane bits 0..4); tie -> lower index.
    // kg=0/1 halves hold different rows; both write their own rows (R8 mapping).
    #pragma unroll
    for (int i = 0; i < 16; ++i) {
        float v  = best[i];
        int   id = bt[i] * 32 + m;               // code index within chunk
        #pragma unroll
        for (int off = 1; off < 32; off <<= 1) {
            float ov = __shfl_xor(v, off, 64);
            int   oi = __shfl_xor(id, off, 64);
            if (ov > v || (ov == v && oi < id)) { v = ov; id = oi; }
        }
        if (m == 0) {
            int row = rowBase + (i & 3) + 8 * (i >> 2) + 4 * kg;
            cand_idx[chunk * N_VOX + row] = chunk * CODES_PER_CHUNK + id;
        }
    }
}

// -------- kernel C: exact fp32 re-score, wave per row (validated R7) ---------
// 64 lanes = 8 candidates x 8 dim-segments. Shuffle-tree dot; cross-candidate
// min with id tie-break (ids ascend with chunk -> first occurrence).
__global__ __launch_bounds__(256) void finalize_kernel(const float* __restrict__ z,
                                                       const float* __restrict__ cb,
                                                       const float* __restrict__ esq,
                                                       const int* __restrict__ cand_idx,
                                                       float* __restrict__ out,
                                                       float* __restrict__ partials) {
    int tid  = threadIdx.x;
    int l    = tid & 63;
    int w    = tid >> 6;
    int row  = blockIdx.x * 4 + w;
    int c    = l >> 3;                 // candidate 0..7
    int s    = l & 7;                  // dim segment 0..7 (8 floats each)

    int id = cand_idx[c * N_VOX + row];

    const float4* zp = (const float4*)(z  + (size_t)row * DIM + s * 8);
    const float4* ep = (const float4*)(cb + (size_t)id  * DIM + s * 8);
    float4 z0 = zp[0], z1 = zp[1], e0 = ep[0], e1 = ep[1];
    float p = z0.x*e0.x + z0.y*e0.y + z0.z*e0.z + z0.w*e0.w
            + z1.x*e1.x + z1.y*e1.y + z1.z*e1.z + z1.w*e1.w;
    #pragma unroll
    for (int off = 1; off < 8; off <<= 1)
        p += __shfl_xor(p, off, 8);    // full dot in all 8 lanes of the group

    float score = esq[id] - 2.0f * p;
    #pragma unroll
    for (int off = 8; off < 64; off <<= 1) {
        float ov = __shfl_xor(score, off, 64);
        int   oi = __shfl_xor(id, off, 64);
        if (ov < score || (ov == score && oi < id)) { score = ov; id = oi; }
    }
    // all 64 lanes hold the winning id for this row

    if (l == 0)
        out[(size_t)N_VOX * DIM + 2 + row] = (float)id;

    // cooperative gather+write: lane handles element l
    float zv = z[(size_t)row * DIM + l];
    float qv = cb[(size_t)id * DIM + l];
    float d  = qv - zv;
    out[(size_t)row * DIM + l] = zv + d;   // mirrors reference z + (q - z)
    float ss = d * d;
    #pragma unroll
    for (int off = 1; off < 64; off <<= 1)
        ss += __shfl_xor(ss, off, 64);

    __shared__ float red[4];
    if (l == 0) red[w] = ss;
    __syncthreads();
    if (tid == 0)
        partials[blockIdx.x] = (red[0] + red[1]) + (red[2] + red[3]);
}

// -------- kernel D: reduce 8192 partials -> both losses --------
__global__ __launch_bounds__(256) void loss_kernel(const float* __restrict__ partials,
                                                   float* __restrict__ out) {
    float s = 0.f;
    #pragma unroll
    for (int i = 0; i < 32; ++i)
        s += partials[threadIdx.x + i * 256];
    __shared__ float red[256];
    red[threadIdx.x] = s;
    __syncthreads();
    #pragma unroll
    for (int st = 128; st > 0; st >>= 1) {
        if (threadIdx.x < st) red[threadIdx.x] += red[threadIdx.x + st];
        __syncthreads();
    }
    if (threadIdx.x == 0) {
        float mean = red[0] / (float)((size_t)N_VOX * DIM);
        out[(size_t)N_VOX * DIM + 0] = mean;
        out[(size_t)N_VOX * DIM + 1] = mean;
    }
}

extern "C" void kernel_launch(void* const* d_in, const int* in_sizes, int n_in,
                              void* d_out, int out_size, void* d_ws, size_t ws_size,
                              hipStream_t stream) {
    const float* z  = (const float*)d_in[0];   // [32768, 64]
    const float* cb = (const float*)d_in[1];   // [8192, 64]
    float* out = (float*)d_out;

    // ws: stream [2 MB] | esq [32 KB] | c0arr [32 KB] | cand_idx [1 MB] | partials [32 KB]
    char*  bstream  = (char*)d_ws;
    float* esq      = (float*)(bstream + (size_t)NTILES * TILE_BYTES);
    float* c0arr    = esq + N_EMB;
    int*   cand_idx = (int*)(c0arr + N_EMB);
    float* partials = (float*)(cand_idx + (size_t)NCHUNK * N_VOX);

    cbprep_kernel  <<<dim3(NTILES * 64 / 256), dim3(256), 0, stream>>>(cb, bstream, esq, c0arr);
    scan_kernel    <<<dim3((N_VOX / 128) * NCHUNK), dim3(256), 0, stream>>>(z, bstream, c0arr, cand_idx);
    finalize_kernel<<<dim3(N_VOX / 4), dim3(256), 0, stream>>>(z, cb, esq, cand_idx, out, partials);
    loss_kernel    <<<1, 256, 0, stream>>>(partials, out);
}